// Round 12
// baseline (123.236 us; speedup 1.0000x reference)
//
#include <hip/hip_runtime.h>
#include <hip/hip_bf16.h>

#define N_NODES 100000
#define N_EDGES 1600000
#define FEAT 128
#define NBINS 2048
#define BIN_NODES 49            // 2048*49 = 100352 >= 100000
#define PBLK 250                // partition blocks (each owns CHUNK edges)
#define CHUNK (N_EDGES / PBLK)  // 6400 (exact)
#define NTBL (NBINS + 1)
#define CSR_MAX 1280            // per-bin edges: mean 784, +17 sigma
#define PREP_BLOCKS (N_NODES * FEAT / 8 / 512)  // 3125 (exact)

typedef __bf16 bf16x8 __attribute__((ext_vector_type(8)));
typedef unsigned short ushort8 __attribute__((ext_vector_type(8)));
typedef float f32x4 __attribute__((ext_vector_type(4)));
typedef float f32x2 __attribute__((ext_vector_type(2)));

__device__ __forceinline__ unsigned short f2bf_bits(float f) {
    unsigned u = __builtin_bit_cast(unsigned, f);
    unsigned r = (u + 0x7fffu + ((u >> 16) & 1u)) >> 16;
    return (unsigned short)r;
}

// ---------------------------------------------------------------------------
// 1) fused prep + partition (independent work, role-split by blockIdx).
// ---------------------------------------------------------------------------
__global__ __launch_bounds__(512) void preppart_kernel(
    const float* __restrict__ x, unsigned short* __restrict__ xbf,
    unsigned int* __restrict__ x8, const int* __restrict__ ei,
    int* __restrict__ offtbl, int* __restrict__ ebin) {
    __shared__ int h[NBINS];   // histogram, then cursors (global positions)
    __shared__ int wsum[8];
    const int tid = threadIdx.x;

    if (blockIdx.x >= PBLK) {
        // ---- prep role ----
        int t = (blockIdx.x - PBLK) * 512 + tid;
        float4 a = ((const float4*)x)[t * 2];
        float4 b = ((const float4*)x)[t * 2 + 1];
        ushort8 u;
        u[0] = f2bf_bits(a.x); u[1] = f2bf_bits(a.y);
        u[2] = f2bf_bits(a.z); u[3] = f2bf_bits(a.w);
        u[4] = f2bf_bits(b.x); u[5] = f2bf_bits(b.y);
        u[6] = f2bf_bits(b.z); u[7] = f2bf_bits(b.w);
        ((ushort8*)xbf)[t] = u;
        int w0 = __builtin_amdgcn_cvt_pk_fp8_f32(a.x, a.y, 0, false);
        w0     = __builtin_amdgcn_cvt_pk_fp8_f32(a.z, a.w, w0, true);
        int w1 = __builtin_amdgcn_cvt_pk_fp8_f32(b.x, b.y, 0, false);
        w1     = __builtin_amdgcn_cvt_pk_fp8_f32(b.z, b.w, w1, true);
        uint2 p; p.x = (unsigned)w0; p.y = (unsigned)w1;
        ((uint2*)x8)[t] = p;
        return;
    }

    // ---- partition role ----
    const int b = blockIdx.x;
    const int lane = tid & 63, wid = tid >> 6;

    for (int i = tid; i < NBINS; i += 512) h[i] = 0;
    __syncthreads();

    const int4* dsts = (const int4*)(ei + N_EDGES + b * CHUNK);
    for (int i = tid; i < CHUNK / 4; i += 512) {
        int4 d = dsts[i];
        atomicAdd(&h[d.x / BIN_NODES], 1);
        atomicAdd(&h[d.y / BIN_NODES], 1);
        atomicAdd(&h[d.z / BIN_NODES], 1);
        atomicAdd(&h[d.w / BIN_NODES], 1);
    }
    __syncthreads();

    // in-block exclusive scan over 2048 counts (4 per thread)
    const int i0 = tid * 4;
    int v0 = h[i0], v1 = h[i0 + 1], v2 = h[i0 + 2], v3 = h[i0 + 3];
    const int s = v0 + v1 + v2 + v3;
    int incl = s;
    #pragma unroll
    for (int d = 1; d < 64; d <<= 1) {
        int up = __shfl_up(incl, d);
        if (lane >= d) incl += up;
    }
    if (lane == 63) wsum[wid] = incl;
    __syncthreads();
    if (tid == 0) {
        int run = 0;
        #pragma unroll
        for (int i = 0; i < 8; ++i) { int v = wsum[i]; wsum[i] = run; run += v; }
    }
    __syncthreads();
    int run = wsum[wid] + incl - s + b * CHUNK;   // global position
    int* otb = offtbl + (size_t)b * NTBL;
    h[i0] = run; otb[i0] = run; run += v0;
    h[i0 + 1] = run; otb[i0 + 1] = run; run += v1;
    h[i0 + 2] = run; otb[i0 + 2] = run; run += v2;
    h[i0 + 3] = run; otb[i0 + 3] = run; run += v3;
    if (tid == 0) otb[NBINS] = (b + 1) * CHUNK;
    __syncthreads();

    // scatter pass: private, cursor-sequential writes
    const int4* srcs = (const int4*)(ei + b * CHUNK);
    for (int i = tid; i < CHUNK / 4; i += 512) {
        int4 s4 = srcs[i];
        int4 d4 = dsts[i];
        int bin, ln, pos;
        bin = d4.x / BIN_NODES; ln = d4.x - bin * BIN_NODES;
        pos = atomicAdd(&h[bin], 1); ebin[pos] = s4.x | (ln << 17);
        bin = d4.y / BIN_NODES; ln = d4.y - bin * BIN_NODES;
        pos = atomicAdd(&h[bin], 1); ebin[pos] = s4.y | (ln << 17);
        bin = d4.z / BIN_NODES; ln = d4.z - bin * BIN_NODES;
        pos = atomicAdd(&h[bin], 1); ebin[pos] = s4.z | (ln << 17);
        bin = d4.w / BIN_NODES; ln = d4.w - bin * BIN_NODES;
        pos = atomicAdd(&h[bin], 1); ebin[pos] = s4.w | (ln << 17);
    }
}

// ---------------------------------------------------------------------------
// 2) per-bin aggregation. XCD-swizzled bins; single global read of ebin into
//    LDS staging; fp8 gather with WIDE loads: 8 lanes x uint4 (16B) per row
//    -> one wave-load covers 8 rows (1 KB), half the vmem/TA requests.
// ---------------------------------------------------------------------------
#define ACC16(v)                                                            \
    {                                                                       \
        acc2[0] += __builtin_amdgcn_cvt_pk_f32_fp8((int)(v).x, false);      \
        acc2[1] += __builtin_amdgcn_cvt_pk_f32_fp8((int)(v).x, true);       \
        acc2[2] += __builtin_amdgcn_cvt_pk_f32_fp8((int)(v).y, false);      \
        acc2[3] += __builtin_amdgcn_cvt_pk_f32_fp8((int)(v).y, true);       \
        acc2[4] += __builtin_amdgcn_cvt_pk_f32_fp8((int)(v).z, false);      \
        acc2[5] += __builtin_amdgcn_cvt_pk_f32_fp8((int)(v).z, true);       \
        acc2[6] += __builtin_amdgcn_cvt_pk_f32_fp8((int)(v).w, false);      \
        acc2[7] += __builtin_amdgcn_cvt_pk_f32_fp8((int)(v).w, true);       \
    }

__global__ __launch_bounds__(256) void agg_kernel(
    const unsigned char* __restrict__ x8, const int* __restrict__ offtbl,
    const int* __restrict__ ebin, unsigned short* __restrict__ xbarbf,
    int* __restrict__ degs) {
    __shared__ int lcnt[BIN_NODES];
    __shared__ int loff[BIN_NODES];
    __shared__ int lcur[BIN_NODES];
    __shared__ int lraw[CSR_MAX];
    __shared__ int lcsr[CSR_MAX];
    __shared__ int wtot[4];

    const int bid = blockIdx.x, tid = threadIdx.x;
    // XCD swizzle: XCD (bid&7) owns bins [(bid&7)*256, ...+256)
    const int b = (bid & 7) * (NBINS / 8) + (bid >> 3);
    int nb = N_NODES - b * BIN_NODES;
    if (nb <= 0) return;          // empty trailing bins
    if (nb > BIN_NODES) nb = BIN_NODES;

    const int lane = tid & 63, wave = tid >> 6;

    // this thread's run (one per partition block)
    int st = 0, L = 0;
    if (tid < PBLK) {
        st = offtbl[(size_t)tid * NTBL + b];
        L  = offtbl[(size_t)tid * NTBL + b + 1] - st;
    }
    if (tid < BIN_NODES) lcnt[tid] = 0;

    // 256-thread exclusive scan of run lengths -> LDS staging offset
    int incl = L;
    #pragma unroll
    for (int d = 1; d < 64; d <<= 1) {
        int up = __shfl_up(incl, d);
        if (lane >= d) incl += up;
    }
    if (lane == 63) wtot[wave] = incl;
    __syncthreads();
    int woff = 0;
    #pragma unroll
    for (int w = 0; w < 4; ++w) woff += (w < wave) ? wtot[w] : 0;
    const int pfx = woff + incl - L;

    // single global read of this bin's edges: copy to lraw + count
    for (int i = 0; i < L; ++i) {
        int v = ebin[st + i];
        lraw[pfx + i] = v;
        atomicAdd(&lcnt[v >> 17], 1);
    }
    __syncthreads();

    // exclusive scan of 49 counters in wave 0
    if (wave == 0) {
        int c = (lane < BIN_NODES) ? lcnt[lane] : 0;
        int ic = c;
        #pragma unroll
        for (int d = 1; d < 64; d <<= 1) {
            int up = __shfl_up(ic, d);
            if (lane >= d) ic += up;
        }
        if (lane < BIN_NODES) {
            loff[lane] = ic - c;
            lcur[lane] = ic - c;
        }
    }
    __syncthreads();

    // ln-scatter entirely from LDS
    for (int i = 0; i < L; ++i) {
        int v = lraw[pfx + i];
        int pos = atomicAdd(&lcur[v >> 17], 1);
        lcsr[pos] = v & 0x1FFFF;
    }
    __syncthreads();

    const int g = lane >> 3;               // row group 0..7
    const unsigned cb = (lane & 7) * 16;   // byte offset in 128 B fp8 row
    for (int ln = wave; ln < nb; ln += 4) {
        const int deg = lcnt[ln];
        const int s0 = loff[ln];
        f32x2 acc2[8];
        #pragma unroll
        for (int i = 0; i < 8; ++i) acc2[i] = (f32x2){0.f, 0.f};
        int base = 0;
        const int full16 = deg & ~15;
        for (; base < full16; base += 16) {
            unsigned sA = (unsigned)lcsr[s0 + base + g];
            unsigned sB = (unsigned)lcsr[s0 + base + 8 + g];
            uint4 va = *(const uint4*)(x8 + ((sA << 7) + cb));
            uint4 vb = *(const uint4*)(x8 + ((sB << 7) + cb));
            ACC16(va); ACC16(vb);
        }
        for (; base < deg; base += 8) {
            int j = base + g;
            bool p = j < deg;
            unsigned sv = (unsigned)(p ? lcsr[s0 + j] : lcsr[s0]);
            uint4 v = *(const uint4*)(x8 + ((sv << 7) + cb));
            if (p) ACC16(v);
        }
        // reduce over the 8 row-groups (lane bits 3,4,5)
        #pragma unroll
        for (int i = 0; i < 8; ++i) {
            #pragma unroll
            for (int k = 0; k < 2; ++k) {
                acc2[i][k] += __shfl_xor(acc2[i][k], 8);
                acc2[i][k] += __shfl_xor(acc2[i][k], 16);
                acc2[i][k] += __shfl_xor(acc2[i][k], 32);
            }
        }
        const int n = b * BIN_NODES + ln;
        if (lane < 8) {
            float inv = 1.0f / (float)(deg > 0 ? deg : 1);
            ushort8 o0, o1;
            #pragma unroll
            for (int i = 0; i < 4; ++i) {
                o0[2 * i]     = f2bf_bits(acc2[i][0] * inv);
                o0[2 * i + 1] = f2bf_bits(acc2[i][1] * inv);
                o1[2 * i]     = f2bf_bits(acc2[4 + i][0] * inv);
                o1[2 * i + 1] = f2bf_bits(acc2[4 + i][1] * inv);
            }
            unsigned short* dst = xbarbf + (size_t)n * FEAT + (lane & 7) * 16;
            *(ushort8*)(dst)     = o0;
            *(ushort8*)(dst + 8) = o1;
        }
        if (lane == 0) degs[n] = deg;
    }
}

// ---------------------------------------------------------------------------
// 3) fused GEMM with XCD-affinity tile mapping: XCD x consumes the xbar rows
//    that agg's XCD x produced (still L2-resident).
// ---------------------------------------------------------------------------
__global__ __launch_bounds__(256) void gemm_kernel(
    const unsigned short* __restrict__ xbf, const unsigned short* __restrict__ xbarbf,
    const float* __restrict__ Wl, const float* __restrict__ bl,
    const float* __restrict__ Wr, const int* __restrict__ degs,
    float* __restrict__ out) {

    __shared__ unsigned short lM[32][136];
    __shared__ unsigned short lX[32][136];

    const int tid = threadIdx.x;
    const int wave = tid >> 6, lane = tid & 63;
    const int l15 = lane & 15, lhi = lane >> 4;
    const int colbase = wave * 32;

    bf16x8 bB[2][8];
    float biasv[2];
    #pragma unroll
    for (int ct = 0; ct < 2; ++ct) {
        int col = colbase + ct * 16 + l15;
        biasv[ct] = bl[col];
        const float* wl = Wl + (size_t)col * 128;
        const float* wr = Wr + (size_t)col * 128;
        #pragma unroll
        for (int s = 0; s < 4; ++s) {
            int kb = lhi * 8 + s * 32;
            bf16x8 bfr, cfr;
            #pragma unroll
            for (int i = 0; i < 8; ++i) {
                bfr[i] = __builtin_bit_cast(__bf16, f2bf_bits(wl[kb + i]));
                cfr[i] = __builtin_bit_cast(__bf16, f2bf_bits(wr[kb + i]));
            }
            bB[ct][s] = bfr;
            bB[ct][4 + s] = cfr;
        }
    }

    // XCD-affinity: 3125 tiles over 8 XCDs; XCD x owns [tile0, tile0+cnt)
    // matching agg's node ranges (x*12544 .. ~). 1024 blocks = 128 per XCD.
    const int xcd = blockIdx.x & 7;
    const int sub = blockIdx.x >> 3;            // 0..127
    const int tile0 = xcd * 390 + (xcd < 5 ? xcd : 5);
    const int cnt = (xcd < 5) ? 391 : 390;
    for (int t = sub; t < cnt; t += 128) {
        const int tile = tile0 + t;
        const int row0 = tile * 32;
        {
            int r = tid >> 3;
            int c0 = (tid & 7) * 16;
            const unsigned short* sm = xbarbf + (size_t)(row0 + r) * FEAT + c0;
            const unsigned short* sx = xbf + (size_t)(row0 + r) * FEAT + c0;
            *(ushort8*)&lM[r][c0]     = *(const ushort8*)(sm);
            *(ushort8*)&lM[r][c0 + 8] = *(const ushort8*)(sm + 8);
            *(ushort8*)&lX[r][c0]     = *(const ushort8*)(sx);
            *(ushort8*)&lX[r][c0 + 8] = *(const ushort8*)(sx + 8);
        }
        __syncthreads();

        f32x4 acc[2][2];
        #pragma unroll
        for (int rh = 0; rh < 2; ++rh)
            #pragma unroll
            for (int ct = 0; ct < 2; ++ct) acc[rh][ct] = (f32x4){0.f, 0.f, 0.f, 0.f};

        #pragma unroll
        for (int rh = 0; rh < 2; ++rh) {
            int arow = rh * 16 + l15;
            bf16x8 aM[4], aX[4];
            #pragma unroll
            for (int s = 0; s < 4; ++s) {
                aM[s] = __builtin_bit_cast(bf16x8, *(const ushort8*)&lM[arow][lhi * 8 + s * 32]);
                aX[s] = __builtin_bit_cast(bf16x8, *(const ushort8*)&lX[arow][lhi * 8 + s * 32]);
            }
            #pragma unroll
            for (int ct = 0; ct < 2; ++ct) {
                f32x4 a = acc[rh][ct];
                #pragma unroll
                for (int s = 0; s < 4; ++s)
                    a = __builtin_amdgcn_mfma_f32_16x16x32_bf16(aM[s], bB[ct][s], a, 0, 0, 0);
                #pragma unroll
                for (int s = 0; s < 4; ++s)
                    a = __builtin_amdgcn_mfma_f32_16x16x32_bf16(aX[s], bB[ct][4 + s], a, 0, 0, 0);
                acc[rh][ct] = a;
            }
        }

        #pragma unroll
        for (int rh = 0; rh < 2; ++rh)
            #pragma unroll
            for (int ct = 0; ct < 2; ++ct) {
                int col = colbase + ct * 16 + l15;
                #pragma unroll
                for (int j = 0; j < 4; ++j) {
                    int r = row0 + rh * 16 + lhi * 4 + j;
                    float bias = (degs[r] > 0) ? biasv[ct] : 0.f;
                    out[(size_t)r * FEAT + col] = acc[rh][ct][j] + bias;
                }
            }
        __syncthreads();
    }
}

extern "C" void kernel_launch(void* const* d_in, const int* in_sizes, int n_in,
                              void* d_out, int out_size, void* d_ws, size_t ws_size,
                              hipStream_t stream) {
    const float* x  = (const float*)d_in[0];
    const int*   ei = (const int*)d_in[1];
    const float* Wl = (const float*)d_in[2];
    const float* bl = (const float*)d_in[3];
    const float* Wr = (const float*)d_in[4];
    float* out = (float*)d_out;

    unsigned short* xbf    = (unsigned short*)d_ws;                  // 25.6 MB
    unsigned short* xbarbf = xbf + (size_t)N_NODES * FEAT;           // 25.6 MB
    unsigned int* x8       = (unsigned int*)(xbarbf + (size_t)N_NODES * FEAT); // 12.8 MB
    int* degs   = (int*)(x8 + (size_t)N_NODES * FEAT / 4);           // 400 KB
    int* offtbl = degs + N_NODES;                                    // 2.05 MB
    int* ebin   = offtbl + (size_t)PBLK * NTBL;                      // 6.4 MB

    preppart_kernel<<<PBLK + PREP_BLOCKS, 512, 0, stream>>>(x, xbf, x8, ei, offtbl, ebin);
    agg_kernel<<<NBINS, 256, 0, stream>>>((const unsigned char*)x8, offtbl, ebin, xbarbf, degs);
    gemm_kernel<<<1024, 256, 0, stream>>>(xbf, xbarbf, Wl, bl, Wr, degs, out);
}

// Round 13
// 96.789 us; speedup vs baseline: 1.2732x; 1.2732x over previous
//
#include <hip/hip_runtime.h>
#include <hip/hip_bf16.h>

#define N_NODES 100000
#define N_EDGES 1600000
#define FEAT 128
#define NBINS 2048
#define BIN_NODES 49            // 2048*49 = 100352 >= 100000
#define PBLK 250                // partition blocks (each owns CHUNK edges)
#define CHUNK (N_EDGES / PBLK)  // 6400 (exact)
#define NTBL (NBINS + 1)
#define CSR_MAX 1280            // per-bin edges: mean 784, +17 sigma
#define PREP_BLOCKS (N_NODES * FEAT / 8 / 512)  // 3125 (exact)

typedef __bf16 bf16x8 __attribute__((ext_vector_type(8)));
typedef unsigned short ushort8 __attribute__((ext_vector_type(8)));
typedef float f32x4 __attribute__((ext_vector_type(4)));
typedef float f32x2 __attribute__((ext_vector_type(2)));

__device__ __forceinline__ unsigned short f2bf_bits(float f) {
    unsigned u = __builtin_bit_cast(unsigned, f);
    unsigned r = (u + 0x7fffu + ((u >> 16) & 1u)) >> 16;
    return (unsigned short)r;
}

// ---------------------------------------------------------------------------
// 1) fused prep + partition (independent work, role-split by blockIdx).
// ---------------------------------------------------------------------------
__global__ __launch_bounds__(512) void preppart_kernel(
    const float* __restrict__ x, unsigned short* __restrict__ xbf,
    unsigned int* __restrict__ x8, const int* __restrict__ ei,
    int* __restrict__ offtbl, int* __restrict__ ebin) {
    __shared__ int h[NBINS];   // histogram, then cursors (global positions)
    __shared__ int wsum[8];
    const int tid = threadIdx.x;

    if (blockIdx.x >= PBLK) {
        // ---- prep role ----
        int t = (blockIdx.x - PBLK) * 512 + tid;
        float4 a = ((const float4*)x)[t * 2];
        float4 b = ((const float4*)x)[t * 2 + 1];
        ushort8 u;
        u[0] = f2bf_bits(a.x); u[1] = f2bf_bits(a.y);
        u[2] = f2bf_bits(a.z); u[3] = f2bf_bits(a.w);
        u[4] = f2bf_bits(b.x); u[5] = f2bf_bits(b.y);
        u[6] = f2bf_bits(b.z); u[7] = f2bf_bits(b.w);
        ((ushort8*)xbf)[t] = u;
        int w0 = __builtin_amdgcn_cvt_pk_fp8_f32(a.x, a.y, 0, false);
        w0     = __builtin_amdgcn_cvt_pk_fp8_f32(a.z, a.w, w0, true);
        int w1 = __builtin_amdgcn_cvt_pk_fp8_f32(b.x, b.y, 0, false);
        w1     = __builtin_amdgcn_cvt_pk_fp8_f32(b.z, b.w, w1, true);
        uint2 p; p.x = (unsigned)w0; p.y = (unsigned)w1;
        ((uint2*)x8)[t] = p;
        return;
    }

    // ---- partition role ----
    const int b = blockIdx.x;
    const int lane = tid & 63, wid = tid >> 6;

    for (int i = tid; i < NBINS; i += 512) h[i] = 0;
    __syncthreads();

    const int4* dsts = (const int4*)(ei + N_EDGES + b * CHUNK);
    for (int i = tid; i < CHUNK / 4; i += 512) {
        int4 d = dsts[i];
        atomicAdd(&h[d.x / BIN_NODES], 1);
        atomicAdd(&h[d.y / BIN_NODES], 1);
        atomicAdd(&h[d.z / BIN_NODES], 1);
        atomicAdd(&h[d.w / BIN_NODES], 1);
    }
    __syncthreads();

    // in-block exclusive scan over 2048 counts (4 per thread)
    const int i0 = tid * 4;
    int v0 = h[i0], v1 = h[i0 + 1], v2 = h[i0 + 2], v3 = h[i0 + 3];
    const int s = v0 + v1 + v2 + v3;
    int incl = s;
    #pragma unroll
    for (int d = 1; d < 64; d <<= 1) {
        int up = __shfl_up(incl, d);
        if (lane >= d) incl += up;
    }
    if (lane == 63) wsum[wid] = incl;
    __syncthreads();
    if (tid == 0) {
        int run = 0;
        #pragma unroll
        for (int i = 0; i < 8; ++i) { int v = wsum[i]; wsum[i] = run; run += v; }
    }
    __syncthreads();
    int run = wsum[wid] + incl - s + b * CHUNK;   // global position
    int* otb = offtbl + (size_t)b * NTBL;
    h[i0] = run; otb[i0] = run; run += v0;
    h[i0 + 1] = run; otb[i0 + 1] = run; run += v1;
    h[i0 + 2] = run; otb[i0 + 2] = run; run += v2;
    h[i0 + 3] = run; otb[i0 + 3] = run; run += v3;
    if (tid == 0) otb[NBINS] = (b + 1) * CHUNK;
    __syncthreads();

    // scatter pass: private, cursor-sequential writes
    const int4* srcs = (const int4*)(ei + b * CHUNK);
    for (int i = tid; i < CHUNK / 4; i += 512) {
        int4 s4 = srcs[i];
        int4 d4 = dsts[i];
        int bin, ln, pos;
        bin = d4.x / BIN_NODES; ln = d4.x - bin * BIN_NODES;
        pos = atomicAdd(&h[bin], 1); ebin[pos] = s4.x | (ln << 17);
        bin = d4.y / BIN_NODES; ln = d4.y - bin * BIN_NODES;
        pos = atomicAdd(&h[bin], 1); ebin[pos] = s4.y | (ln << 17);
        bin = d4.z / BIN_NODES; ln = d4.z - bin * BIN_NODES;
        pos = atomicAdd(&h[bin], 1); ebin[pos] = s4.z | (ln << 17);
        bin = d4.w / BIN_NODES; ln = d4.w - bin * BIN_NODES;
        pos = atomicAdd(&h[bin], 1); ebin[pos] = s4.w | (ln << 17);
    }
}

// ---------------------------------------------------------------------------
// 2) per-bin aggregation. 16 lanes x uint2 per row; single 16-row loop with
//    4 predicated independent loads per iteration (max MLP in all cases).
// ---------------------------------------------------------------------------
#define ACC8(v)                                                             \
    {                                                                       \
        acc2[0] += __builtin_amdgcn_cvt_pk_f32_fp8((int)(v).x, false);      \
        acc2[1] += __builtin_amdgcn_cvt_pk_f32_fp8((int)(v).x, true);       \
        acc2[2] += __builtin_amdgcn_cvt_pk_f32_fp8((int)(v).y, false);      \
        acc2[3] += __builtin_amdgcn_cvt_pk_f32_fp8((int)(v).y, true);       \
    }

__global__ __launch_bounds__(256) void agg_kernel(
    const unsigned char* __restrict__ x8, const int* __restrict__ offtbl,
    const int* __restrict__ ebin, unsigned short* __restrict__ xbarbf,
    int* __restrict__ degs) {
    __shared__ int lcnt[BIN_NODES];
    __shared__ int loff[BIN_NODES];
    __shared__ int lcur[BIN_NODES];
    __shared__ int lraw[CSR_MAX];
    __shared__ int lcsr[CSR_MAX];
    __shared__ int wtot[4];

    const int bid = blockIdx.x, tid = threadIdx.x;
    // XCD swizzle: XCD (bid&7) owns bins [(bid&7)*256, ...+256)
    const int b = (bid & 7) * (NBINS / 8) + (bid >> 3);
    int nb = N_NODES - b * BIN_NODES;
    if (nb <= 0) return;          // empty trailing bins
    if (nb > BIN_NODES) nb = BIN_NODES;

    const int lane = tid & 63, wave = tid >> 6;

    // this thread's run (one per partition block)
    int st = 0, L = 0;
    if (tid < PBLK) {
        st = offtbl[(size_t)tid * NTBL + b];
        L  = offtbl[(size_t)tid * NTBL + b + 1] - st;
    }
    if (tid < BIN_NODES) lcnt[tid] = 0;

    // 256-thread exclusive scan of run lengths -> LDS staging offset
    int incl = L;
    #pragma unroll
    for (int d = 1; d < 64; d <<= 1) {
        int up = __shfl_up(incl, d);
        if (lane >= d) incl += up;
    }
    if (lane == 63) wtot[wave] = incl;
    __syncthreads();
    int woff = 0;
    #pragma unroll
    for (int w = 0; w < 4; ++w) woff += (w < wave) ? wtot[w] : 0;
    const int pfx = woff + incl - L;

    // single global read of this bin's edges: copy to lraw + count
    for (int i = 0; i < L; ++i) {
        int v = ebin[st + i];
        lraw[pfx + i] = v;
        atomicAdd(&lcnt[v >> 17], 1);
    }
    __syncthreads();

    // exclusive scan of 49 counters in wave 0
    if (wave == 0) {
        int c = (lane < BIN_NODES) ? lcnt[lane] : 0;
        int ic = c;
        #pragma unroll
        for (int d = 1; d < 64; d <<= 1) {
            int up = __shfl_up(ic, d);
            if (lane >= d) ic += up;
        }
        if (lane < BIN_NODES) {
            loff[lane] = ic - c;
            lcur[lane] = ic - c;
        }
    }
    __syncthreads();

    // ln-scatter entirely from LDS
    for (int i = 0; i < L; ++i) {
        int v = lraw[pfx + i];
        int pos = atomicAdd(&lcur[v >> 17], 1);
        lcsr[pos] = v & 0x1FFFF;
    }
    __syncthreads();

    const int g = lane >> 4;               // row group 0..3
    const unsigned c8 = (lane & 15) * 8;   // byte offset in 128 B fp8 row
    for (int ln = wave; ln < nb; ln += 4) {
        const int deg = lcnt[ln];
        const int s0 = loff[ln];
        f32x2 acc2[4];
        #pragma unroll
        for (int i = 0; i < 4; ++i) acc2[i] = (f32x2){0.f, 0.f};
        // 16 rows / 4 independent predicated loads per iteration
        for (int base = 0; base < deg; base += 16) {
            int j0 = base + g, j1 = j0 + 4, j2 = j0 + 8, j3 = j0 + 12;
            bool pA = j0 < deg, pB = j1 < deg, pC = j2 < deg, pD = j3 < deg;
            unsigned sA = (unsigned)(pA ? lcsr[s0 + j0] : lcsr[s0]);
            unsigned sB = (unsigned)(pB ? lcsr[s0 + j1] : lcsr[s0]);
            unsigned sC = (unsigned)(pC ? lcsr[s0 + j2] : lcsr[s0]);
            unsigned sD = (unsigned)(pD ? lcsr[s0 + j3] : lcsr[s0]);
            uint2 va = *(const uint2*)(x8 + ((sA << 7) + c8));
            uint2 vb = *(const uint2*)(x8 + ((sB << 7) + c8));
            uint2 vc = *(const uint2*)(x8 + ((sC << 7) + c8));
            uint2 vd = *(const uint2*)(x8 + ((sD << 7) + c8));
            if (pA) ACC8(va);
            if (pB) ACC8(vb);
            if (pC) ACC8(vc);
            if (pD) ACC8(vd);
        }
        #pragma unroll
        for (int i = 0; i < 4; ++i) {
            #pragma unroll
            for (int k = 0; k < 2; ++k) {
                acc2[i][k] += __shfl_xor(acc2[i][k], 16);
                acc2[i][k] += __shfl_xor(acc2[i][k], 32);
            }
        }
        const int n = b * BIN_NODES + ln;
        if (lane < 16) {
            float inv = 1.0f / (float)(deg > 0 ? deg : 1);
            ushort8 o;
            #pragma unroll
            for (int i = 0; i < 4; ++i) {
                o[2 * i]     = f2bf_bits(acc2[i][0] * inv);
                o[2 * i + 1] = f2bf_bits(acc2[i][1] * inv);
            }
            *(ushort8*)(xbarbf + (size_t)n * FEAT + c8) = o;
        }
        if (lane == 0) degs[n] = deg;
    }
}

// ---------------------------------------------------------------------------
// 3) fused GEMM with XCD-affinity tile mapping: XCD x consumes the xbar rows
//    that agg's XCD x produced (still L2-resident).
// ---------------------------------------------------------------------------
__global__ __launch_bounds__(256) void gemm_kernel(
    const unsigned short* __restrict__ xbf, const unsigned short* __restrict__ xbarbf,
    const float* __restrict__ Wl, const float* __restrict__ bl,
    const float* __restrict__ Wr, const int* __restrict__ degs,
    float* __restrict__ out) {

    __shared__ unsigned short lM[32][136];
    __shared__ unsigned short lX[32][136];

    const int tid = threadIdx.x;
    const int wave = tid >> 6, lane = tid & 63;
    const int l15 = lane & 15, lhi = lane >> 4;
    const int colbase = wave * 32;

    bf16x8 bB[2][8];
    float biasv[2];
    #pragma unroll
    for (int ct = 0; ct < 2; ++ct) {
        int col = colbase + ct * 16 + l15;
        biasv[ct] = bl[col];
        const float* wl = Wl + (size_t)col * 128;
        const float* wr = Wr + (size_t)col * 128;
        #pragma unroll
        for (int s = 0; s < 4; ++s) {
            int kb = lhi * 8 + s * 32;
            bf16x8 bfr, cfr;
            #pragma unroll
            for (int i = 0; i < 8; ++i) {
                bfr[i] = __builtin_bit_cast(__bf16, f2bf_bits(wl[kb + i]));
                cfr[i] = __builtin_bit_cast(__bf16, f2bf_bits(wr[kb + i]));
            }
            bB[ct][s] = bfr;
            bB[ct][4 + s] = cfr;
        }
    }

    // XCD-affinity: 3125 tiles over 8 XCDs; XCD x owns [tile0, tile0+cnt)
    const int xcd = blockIdx.x & 7;
    const int sub = blockIdx.x >> 3;            // 0..127
    const int tile0 = xcd * 390 + (xcd < 5 ? xcd : 5);
    const int cnt = (xcd < 5) ? 391 : 390;
    for (int t = sub; t < cnt; t += 128) {
        const int tile = tile0 + t;
        const int row0 = tile * 32;
        {
            int r = tid >> 3;
            int c0 = (tid & 7) * 16;
            const unsigned short* sm = xbarbf + (size_t)(row0 + r) * FEAT + c0;
            const unsigned short* sx = xbf + (size_t)(row0 + r) * FEAT + c0;
            *(ushort8*)&lM[r][c0]     = *(const ushort8*)(sm);
            *(ushort8*)&lM[r][c0 + 8] = *(const ushort8*)(sm + 8);
            *(ushort8*)&lX[r][c0]     = *(const ushort8*)(sx);
            *(ushort8*)&lX[r][c0 + 8] = *(const ushort8*)(sx + 8);
        }
        __syncthreads();

        f32x4 acc[2][2];
        #pragma unroll
        for (int rh = 0; rh < 2; ++rh)
            #pragma unroll
            for (int ct = 0; ct < 2; ++ct) acc[rh][ct] = (f32x4){0.f, 0.f, 0.f, 0.f};

        #pragma unroll
        for (int rh = 0; rh < 2; ++rh) {
            int arow = rh * 16 + l15;
            bf16x8 aM[4], aX[4];
            #pragma unroll
            for (int s = 0; s < 4; ++s) {
                aM[s] = __builtin_bit_cast(bf16x8, *(const ushort8*)&lM[arow][lhi * 8 + s * 32]);
                aX[s] = __builtin_bit_cast(bf16x8, *(const ushort8*)&lX[arow][lhi * 8 + s * 32]);
            }
            #pragma unroll
            for (int ct = 0; ct < 2; ++ct) {
                f32x4 a = acc[rh][ct];
                #pragma unroll
                for (int s = 0; s < 4; ++s)
                    a = __builtin_amdgcn_mfma_f32_16x16x32_bf16(aM[s], bB[ct][s], a, 0, 0, 0);
                #pragma unroll
                for (int s = 0; s < 4; ++s)
                    a = __builtin_amdgcn_mfma_f32_16x16x32_bf16(aX[s], bB[ct][4 + s], a, 0, 0, 0);
                acc[rh][ct] = a;
            }
        }

        #pragma unroll
        for (int rh = 0; rh < 2; ++rh)
            #pragma unroll
            for (int ct = 0; ct < 2; ++ct) {
                int col = colbase + ct * 16 + l15;
                #pragma unroll
                for (int j = 0; j < 4; ++j) {
                    int r = row0 + rh * 16 + lhi * 4 + j;
                    float bias = (degs[r] > 0) ? biasv[ct] : 0.f;
                    out[(size_t)r * FEAT + col] = acc[rh][ct][j] + bias;
                }
            }
        __syncthreads();
    }
}

extern "C" void kernel_launch(void* const* d_in, const int* in_sizes, int n_in,
                              void* d_out, int out_size, void* d_ws, size_t ws_size,
                              hipStream_t stream) {
    const float* x  = (const float*)d_in[0];
    const int*   ei = (const int*)d_in[1];
    const float* Wl = (const float*)d_in[2];
    const float* bl = (const float*)d_in[3];
    const float* Wr = (const float*)d_in[4];
    float* out = (float*)d_out;

    unsigned short* xbf    = (unsigned short*)d_ws;                  // 25.6 MB
    unsigned short* xbarbf = xbf + (size_t)N_NODES * FEAT;           // 25.6 MB
    unsigned int* x8       = (unsigned int*)(xbarbf + (size_t)N_NODES * FEAT); // 12.8 MB
    int* degs   = (int*)(x8 + (size_t)N_NODES * FEAT / 4);           // 400 KB
    int* offtbl = degs + N_NODES;                                    // 2.05 MB
    int* ebin   = offtbl + (size_t)PBLK * NTBL;                      // 6.4 MB

    preppart_kernel<<<PBLK + PREP_BLOCKS, 512, 0, stream>>>(x, xbf, x8, ei, offtbl, ebin);
    agg_kernel<<<NBINS, 256, 0, stream>>>((const unsigned char*)x8, offtbl, ebin, xbarbf, degs);
    gemm_kernel<<<1024, 256, 0, stream>>>(xbf, xbarbf, Wl, bl, Wr, degs, out);
}

// Round 14
// 91.154 us; speedup vs baseline: 1.3520x; 1.0618x over previous
//
#include <hip/hip_runtime.h>
#include <hip/hip_bf16.h>

#define N_NODES 100000
#define N_EDGES 1600000
#define FEAT 128
#define NBINS 2048
#define BIN_NODES 49            // 2048*49 = 100352 >= 100000
#define PBLK 250                // partition blocks (each owns CHUNK edges)
#define CHUNK (N_EDGES / PBLK)  // 6400 (exact)
#define NTBL (NBINS + 1)
#define CSR_MAX 1280            // per-bin edges: mean 784, +17 sigma
#define PREP_BLOCKS (N_NODES * FEAT / 8 / 512)  // 3125 (exact)
#define WCONV_BLOCKS 8          // weight bf16-conversion blocks

typedef __bf16 bf16x8 __attribute__((ext_vector_type(8)));
typedef unsigned short ushort8 __attribute__((ext_vector_type(8)));
typedef float f32x4 __attribute__((ext_vector_type(4)));
typedef float f32x2 __attribute__((ext_vector_type(2)));

__device__ __forceinline__ unsigned short f2bf_bits(float f) {
    unsigned u = __builtin_bit_cast(unsigned, f);
    unsigned r = (u + 0x7fffu + ((u >> 16) & 1u)) >> 16;
    return (unsigned short)r;
}

__device__ __forceinline__ ushort8 cvt8(float4 a, float4 b) {
    ushort8 u;
    u[0] = f2bf_bits(a.x); u[1] = f2bf_bits(a.y);
    u[2] = f2bf_bits(a.z); u[3] = f2bf_bits(a.w);
    u[4] = f2bf_bits(b.x); u[5] = f2bf_bits(b.y);
    u[6] = f2bf_bits(b.z); u[7] = f2bf_bits(b.w);
    return u;
}

// ---------------------------------------------------------------------------
// 1) fused prep + partition + weight-conversion (role-split by blockIdx).
// ---------------------------------------------------------------------------
__global__ __launch_bounds__(512) void preppart_kernel(
    const float* __restrict__ x, unsigned short* __restrict__ xbf,
    unsigned int* __restrict__ x8, const int* __restrict__ ei,
    int* __restrict__ offtbl, int* __restrict__ ebin,
    const float* __restrict__ Wl, const float* __restrict__ Wr,
    unsigned short* __restrict__ wlbf, unsigned short* __restrict__ wrbf) {
    __shared__ int h[NBINS];   // histogram, then cursors (global positions)
    __shared__ int wsum[8];
    const int tid = threadIdx.x;

    if (blockIdx.x >= PBLK + PREP_BLOCKS) {
        // ---- weight-conversion role: 32768 elems across Wl,Wr ----
        int t = (blockIdx.x - PBLK - PREP_BLOCKS) * 512 + tid;  // 0..4095
        const float* src;
        unsigned short* dst;
        int off;
        if (t < 2048) { src = Wl; dst = wlbf; off = t * 8; }
        else          { src = Wr; dst = wrbf; off = (t - 2048) * 8; }
        float4 a = *(const float4*)(src + off);
        float4 b = *(const float4*)(src + off + 4);
        *(ushort8*)(dst + off) = cvt8(a, b);
        return;
    }

    if (blockIdx.x >= PBLK) {
        // ---- prep role ----
        int t = (blockIdx.x - PBLK) * 512 + tid;
        float4 a = ((const float4*)x)[t * 2];
        float4 b = ((const float4*)x)[t * 2 + 1];
        ((ushort8*)xbf)[t] = cvt8(a, b);
        int w0 = __builtin_amdgcn_cvt_pk_fp8_f32(a.x, a.y, 0, false);
        w0     = __builtin_amdgcn_cvt_pk_fp8_f32(a.z, a.w, w0, true);
        int w1 = __builtin_amdgcn_cvt_pk_fp8_f32(b.x, b.y, 0, false);
        w1     = __builtin_amdgcn_cvt_pk_fp8_f32(b.z, b.w, w1, true);
        uint2 p; p.x = (unsigned)w0; p.y = (unsigned)w1;
        ((uint2*)x8)[t] = p;
        return;
    }

    // ---- partition role ----
    const int b = blockIdx.x;
    const int lane = tid & 63, wid = tid >> 6;

    for (int i = tid; i < NBINS; i += 512) h[i] = 0;
    __syncthreads();

    const int4* dsts = (const int4*)(ei + N_EDGES + b * CHUNK);
    for (int i = tid; i < CHUNK / 4; i += 512) {
        int4 d = dsts[i];
        atomicAdd(&h[d.x / BIN_NODES], 1);
        atomicAdd(&h[d.y / BIN_NODES], 1);
        atomicAdd(&h[d.z / BIN_NODES], 1);
        atomicAdd(&h[d.w / BIN_NODES], 1);
    }
    __syncthreads();

    // in-block exclusive scan over 2048 counts (4 per thread)
    const int i0 = tid * 4;
    int v0 = h[i0], v1 = h[i0 + 1], v2 = h[i0 + 2], v3 = h[i0 + 3];
    const int s = v0 + v1 + v2 + v3;
    int incl = s;
    #pragma unroll
    for (int d = 1; d < 64; d <<= 1) {
        int up = __shfl_up(incl, d);
        if (lane >= d) incl += up;
    }
    if (lane == 63) wsum[wid] = incl;
    __syncthreads();
    if (tid == 0) {
        int run = 0;
        #pragma unroll
        for (int i = 0; i < 8; ++i) { int v = wsum[i]; wsum[i] = run; run += v; }
    }
    __syncthreads();
    int run = wsum[wid] + incl - s + b * CHUNK;   // global position
    int* otb = offtbl + (size_t)b * NTBL;
    h[i0] = run; otb[i0] = run; run += v0;
    h[i0 + 1] = run; otb[i0 + 1] = run; run += v1;
    h[i0 + 2] = run; otb[i0 + 2] = run; run += v2;
    h[i0 + 3] = run; otb[i0 + 3] = run; run += v3;
    if (tid == 0) otb[NBINS] = (b + 1) * CHUNK;
    __syncthreads();

    // scatter pass: private, cursor-sequential writes
    const int4* srcs = (const int4*)(ei + b * CHUNK);
    for (int i = tid; i < CHUNK / 4; i += 512) {
        int4 s4 = srcs[i];
        int4 d4 = dsts[i];
        int bin, ln, pos;
        bin = d4.x / BIN_NODES; ln = d4.x - bin * BIN_NODES;
        pos = atomicAdd(&h[bin], 1); ebin[pos] = s4.x | (ln << 17);
        bin = d4.y / BIN_NODES; ln = d4.y - bin * BIN_NODES;
        pos = atomicAdd(&h[bin], 1); ebin[pos] = s4.y | (ln << 17);
        bin = d4.z / BIN_NODES; ln = d4.z - bin * BIN_NODES;
        pos = atomicAdd(&h[bin], 1); ebin[pos] = s4.z | (ln << 17);
        bin = d4.w / BIN_NODES; ln = d4.w - bin * BIN_NODES;
        pos = atomicAdd(&h[bin], 1); ebin[pos] = s4.w | (ln << 17);
    }
}

// ---------------------------------------------------------------------------
// 2) per-bin aggregation. 16 lanes x uint2 per row; 32-row loop with
//    8 predicated independent loads per iteration (MLP = 8).
// ---------------------------------------------------------------------------
#define ACC8(v)                                                             \
    {                                                                       \
        acc2[0] += __builtin_amdgcn_cvt_pk_f32_fp8((int)(v).x, false);      \
        acc2[1] += __builtin_amdgcn_cvt_pk_f32_fp8((int)(v).x, true);       \
        acc2[2] += __builtin_amdgcn_cvt_pk_f32_fp8((int)(v).y, false);      \
        acc2[3] += __builtin_amdgcn_cvt_pk_f32_fp8((int)(v).y, true);       \
    }

__global__ __launch_bounds__(256) void agg_kernel(
    const unsigned char* __restrict__ x8, const int* __restrict__ offtbl,
    const int* __restrict__ ebin, unsigned short* __restrict__ xbarbf,
    int* __restrict__ degs) {
    __shared__ int lcnt[BIN_NODES];
    __shared__ int loff[BIN_NODES];
    __shared__ int lcur[BIN_NODES];
    __shared__ int lraw[CSR_MAX];
    __shared__ int lcsr[CSR_MAX];
    __shared__ int wtot[4];

    const int bid = blockIdx.x, tid = threadIdx.x;
    // XCD swizzle: XCD (bid&7) owns bins [(bid&7)*256, ...+256)
    const int b = (bid & 7) * (NBINS / 8) + (bid >> 3);
    int nb = N_NODES - b * BIN_NODES;
    if (nb <= 0) return;          // empty trailing bins
    if (nb > BIN_NODES) nb = BIN_NODES;

    const int lane = tid & 63, wave = tid >> 6;

    // this thread's run (one per partition block)
    int st = 0, L = 0;
    if (tid < PBLK) {
        st = offtbl[(size_t)tid * NTBL + b];
        L  = offtbl[(size_t)tid * NTBL + b + 1] - st;
    }
    if (tid < BIN_NODES) lcnt[tid] = 0;

    // 256-thread exclusive scan of run lengths -> LDS staging offset
    int incl = L;
    #pragma unroll
    for (int d = 1; d < 64; d <<= 1) {
        int up = __shfl_up(incl, d);
        if (lane >= d) incl += up;
    }
    if (lane == 63) wtot[wave] = incl;
    __syncthreads();
    int woff = 0;
    #pragma unroll
    for (int w = 0; w < 4; ++w) woff += (w < wave) ? wtot[w] : 0;
    const int pfx = woff + incl - L;

    // single global read of this bin's edges: copy to lraw + count
    for (int i = 0; i < L; ++i) {
        int v = ebin[st + i];
        lraw[pfx + i] = v;
        atomicAdd(&lcnt[v >> 17], 1);
    }
    __syncthreads();

    // exclusive scan of 49 counters in wave 0
    if (wave == 0) {
        int c = (lane < BIN_NODES) ? lcnt[lane] : 0;
        int ic = c;
        #pragma unroll
        for (int d = 1; d < 64; d <<= 1) {
            int up = __shfl_up(ic, d);
            if (lane >= d) ic += up;
        }
        if (lane < BIN_NODES) {
            loff[lane] = ic - c;
            lcur[lane] = ic - c;
        }
    }
    __syncthreads();

    // ln-scatter entirely from LDS
    for (int i = 0; i < L; ++i) {
        int v = lraw[pfx + i];
        int pos = atomicAdd(&lcur[v >> 17], 1);
        lcsr[pos] = v & 0x1FFFF;
    }
    __syncthreads();

    const int g = lane >> 4;               // row group 0..3
    const unsigned c8 = (lane & 15) * 8;   // byte offset in 128 B fp8 row
    for (int ln = wave; ln < nb; ln += 4) {
        const int deg = lcnt[ln];
        const int off = loff[ln];
        f32x2 acc2[4];
        #pragma unroll
        for (int i = 0; i < 4; ++i) acc2[i] = (f32x2){0.f, 0.f};
        // 32 rows / 8 independent predicated loads per iteration
        for (int base = 0; base < deg; base += 32) {
            int j0 = base + g;
            bool p0 = j0 < deg,       p1 = j0 + 4 < deg,  p2 = j0 + 8 < deg;
            bool p3 = j0 + 12 < deg,  p4 = j0 + 16 < deg, p5 = j0 + 20 < deg;
            bool p6 = j0 + 24 < deg,  p7 = j0 + 28 < deg;
            unsigned sA = (unsigned)(p0 ? lcsr[off + j0]      : lcsr[off]);
            unsigned sB = (unsigned)(p1 ? lcsr[off + j0 + 4]  : lcsr[off]);
            unsigned sC = (unsigned)(p2 ? lcsr[off + j0 + 8]  : lcsr[off]);
            unsigned sD = (unsigned)(p3 ? lcsr[off + j0 + 12] : lcsr[off]);
            unsigned sE = (unsigned)(p4 ? lcsr[off + j0 + 16] : lcsr[off]);
            unsigned sF = (unsigned)(p5 ? lcsr[off + j0 + 20] : lcsr[off]);
            unsigned sG = (unsigned)(p6 ? lcsr[off + j0 + 24] : lcsr[off]);
            unsigned sH = (unsigned)(p7 ? lcsr[off + j0 + 28] : lcsr[off]);
            uint2 va = *(const uint2*)(x8 + ((sA << 7) + c8));
            uint2 vb = *(const uint2*)(x8 + ((sB << 7) + c8));
            uint2 vc = *(const uint2*)(x8 + ((sC << 7) + c8));
            uint2 vd = *(const uint2*)(x8 + ((sD << 7) + c8));
            uint2 ve = *(const uint2*)(x8 + ((sE << 7) + c8));
            uint2 vf = *(const uint2*)(x8 + ((sF << 7) + c8));
            uint2 vg = *(const uint2*)(x8 + ((sG << 7) + c8));
            uint2 vh = *(const uint2*)(x8 + ((sH << 7) + c8));
            if (p0) ACC8(va);
            if (p1) ACC8(vb);
            if (p2) ACC8(vc);
            if (p3) ACC8(vd);
            if (p4) ACC8(ve);
            if (p5) ACC8(vf);
            if (p6) ACC8(vg);
            if (p7) ACC8(vh);
        }
        #pragma unroll
        for (int i = 0; i < 4; ++i) {
            #pragma unroll
            for (int k = 0; k < 2; ++k) {
                acc2[i][k] += __shfl_xor(acc2[i][k], 16);
                acc2[i][k] += __shfl_xor(acc2[i][k], 32);
            }
        }
        const int n = b * BIN_NODES + ln;
        if (lane < 16) {
            float inv = 1.0f / (float)(deg > 0 ? deg : 1);
            ushort8 o;
            #pragma unroll
            for (int i = 0; i < 4; ++i) {
                o[2 * i]     = f2bf_bits(acc2[i][0] * inv);
                o[2 * i + 1] = f2bf_bits(acc2[i][1] * inv);
            }
            *(ushort8*)(xbarbf + (size_t)n * FEAT + c8) = o;
        }
        if (lane == 0) degs[n] = deg;
    }
}

// ---------------------------------------------------------------------------
// 3) fused GEMM (bf16 weights preconverted): B-frag init = 1 ushort8 load.
// ---------------------------------------------------------------------------
__global__ __launch_bounds__(256) void gemm_kernel(
    const unsigned short* __restrict__ xbf, const unsigned short* __restrict__ xbarbf,
    const unsigned short* __restrict__ wlbf, const float* __restrict__ bl,
    const unsigned short* __restrict__ wrbf, const int* __restrict__ degs,
    float* __restrict__ out) {

    __shared__ unsigned short lM[32][136];
    __shared__ unsigned short lX[32][136];

    const int tid = threadIdx.x;
    const int wave = tid >> 6, lane = tid & 63;
    const int l15 = lane & 15, lhi = lane >> 4;
    const int colbase = wave * 32;

    bf16x8 bB[2][8];
    float biasv[2];
    #pragma unroll
    for (int ct = 0; ct < 2; ++ct) {
        int col = colbase + ct * 16 + l15;
        biasv[ct] = bl[col];
        #pragma unroll
        for (int s = 0; s < 4; ++s) {
            int kb = lhi * 8 + s * 32;
            bB[ct][s]     = __builtin_bit_cast(bf16x8, *(const ushort8*)(wlbf + col * 128 + kb));
            bB[ct][4 + s] = __builtin_bit_cast(bf16x8, *(const ushort8*)(wrbf + col * 128 + kb));
        }
    }

    // XCD-affinity: 3125 tiles over 8 XCDs; XCD x owns [tile0, tile0+cnt)
    const int xcd = blockIdx.x & 7;
    const int sub = blockIdx.x >> 3;            // 0..127
    const int tile0 = xcd * 390 + (xcd < 5 ? xcd : 5);
    const int cnt = (xcd < 5) ? 391 : 390;
    for (int t = sub; t < cnt; t += 128) {
        const int tile = tile0 + t;
        const int row0 = tile * 32;
        {
            int r = tid >> 3;
            int c0 = (tid & 7) * 16;
            const unsigned short* sm = xbarbf + (size_t)(row0 + r) * FEAT + c0;
            const unsigned short* sx = xbf + (size_t)(row0 + r) * FEAT + c0;
            *(ushort8*)&lM[r][c0]     = *(const ushort8*)(sm);
            *(ushort8*)&lM[r][c0 + 8] = *(const ushort8*)(sm + 8);
            *(ushort8*)&lX[r][c0]     = *(const ushort8*)(sx);
            *(ushort8*)&lX[r][c0 + 8] = *(const ushort8*)(sx + 8);
        }
        __syncthreads();

        f32x4 acc[2][2];
        #pragma unroll
        for (int rh = 0; rh < 2; ++rh)
            #pragma unroll
            for (int ct = 0; ct < 2; ++ct) acc[rh][ct] = (f32x4){0.f, 0.f, 0.f, 0.f};

        #pragma unroll
        for (int rh = 0; rh < 2; ++rh) {
            int arow = rh * 16 + l15;
            bf16x8 aM[4], aX[4];
            #pragma unroll
            for (int s = 0; s < 4; ++s) {
                aM[s] = __builtin_bit_cast(bf16x8, *(const ushort8*)&lM[arow][lhi * 8 + s * 32]);
                aX[s] = __builtin_bit_cast(bf16x8, *(const ushort8*)&lX[arow][lhi * 8 + s * 32]);
            }
            #pragma unroll
            for (int ct = 0; ct < 2; ++ct) {
                f32x4 a = acc[rh][ct];
                #pragma unroll
                for (int s = 0; s < 4; ++s)
                    a = __builtin_amdgcn_mfma_f32_16x16x32_bf16(aM[s], bB[ct][s], a, 0, 0, 0);
                #pragma unroll
                for (int s = 0; s < 4; ++s)
                    a = __builtin_amdgcn_mfma_f32_16x16x32_bf16(aX[s], bB[ct][4 + s], a, 0, 0, 0);
                acc[rh][ct] = a;
            }
        }

        #pragma unroll
        for (int rh = 0; rh < 2; ++rh)
            #pragma unroll
            for (int ct = 0; ct < 2; ++ct) {
                int col = colbase + ct * 16 + l15;
                #pragma unroll
                for (int j = 0; j < 4; ++j) {
                    int r = row0 + rh * 16 + lhi * 4 + j;
                    float bias = (degs[r] > 0) ? biasv[ct] : 0.f;
                    out[(size_t)r * FEAT + col] = acc[rh][ct][j] + bias;
                }
            }
        __syncthreads();
    }
}

extern "C" void kernel_launch(void* const* d_in, const int* in_sizes, int n_in,
                              void* d_out, int out_size, void* d_ws, size_t ws_size,
                              hipStream_t stream) {
    const float* x  = (const float*)d_in[0];
    const int*   ei = (const int*)d_in[1];
    const float* Wl = (const float*)d_in[2];
    const float* bl = (const float*)d_in[3];
    const float* Wr = (const float*)d_in[4];
    float* out = (float*)d_out;

    unsigned short* xbf    = (unsigned short*)d_ws;                  // 25.6 MB
    unsigned short* xbarbf = xbf + (size_t)N_NODES * FEAT;           // 25.6 MB
    unsigned int* x8       = (unsigned int*)(xbarbf + (size_t)N_NODES * FEAT); // 12.8 MB
    int* degs   = (int*)(x8 + (size_t)N_NODES * FEAT / 4);           // 400 KB
    int* offtbl = degs + N_NODES;                                    // 2.05 MB
    unsigned short* wlbf = (unsigned short*)(offtbl + (size_t)PBLK * NTBL); // 32 KB
    unsigned short* wrbf = wlbf + 16384;                             // 32 KB
    int* ebin   = (int*)(wrbf + 16384);                              // 6.4 MB

    preppart_kernel<<<PBLK + PREP_BLOCKS + WCONV_BLOCKS, 512, 0, stream>>>(
        x, xbf, x8, ei, offtbl, ebin, Wl, Wr, wlbf, wrbf);
    agg_kernel<<<NBINS, 256, 0, stream>>>((const unsigned char*)x8, offtbl, ebin, xbarbf, degs);
    gemm_kernel<<<1024, 256, 0, stream>>>(xbf, xbarbf, wlbf, bl, wrbf, degs, out);
}